// Round 1
// 262.539 us; speedup vs baseline: 1.0176x; 1.0176x over previous
//
#include <hip/hip_runtime.h>
#include <hip/hip_bf16.h>

// ---------------------------------------------------------------------------
// QLSTM: seq=256, batch=512, input=256, H=n_qubits=8.
// Kernel 1 (MFMA, persistent — UNCHANGED, verified): Z[row][kq*4+g].
// Kernel 2 (scan): 16 lanes/batch, NEW lane map q = 2*kq + hi.
//   - prefix-product selects folded into DPP bound_ctrl (row edge == group edge)
//   - gates broadcast to all lanes via quad_perm -> no SWAP8/REPL8 tail
//   - cx/hx pair-duplicated valid in all lanes; rotations use row_ror 2s
// ---------------------------------------------------------------------------

#define SEQ   256
#define BATCH 512
#define DIN   256
#define NROWS (SEQ * BATCH)      // 131072
#define DCOMB 264                // 256 + 8
#define MCHUNKS 4                // 64-row chunks per block (512 blocks)

typedef __attribute__((ext_vector_type(8))) short short8;
typedef __attribute__((ext_vector_type(4))) float f32x4;
typedef __attribute__((ext_vector_type(2))) float f32x2;

__device__ __forceinline__ short f2bf(float f) {
    union { __hip_bfloat16 h; short s; } u;
    u.h = __float2bfloat16(f);
    return u.s;
}
__device__ __forceinline__ float bf2f(short s) {
    union { short s; __hip_bfloat16 h; } u;
    u.s = s;
    return __bfloat162float(u.h);
}

// ------------------------------ kernel 1: gemm -----------------------------
__device__ __forceinline__ short8 pack8(float4 a, float4 b) {
    union { short8 s8; int i[4]; } u;
    union { __hip_bfloat162 h; int i; } v;
    v.h = __float22bfloat162_rn(make_float2(a.x, a.y)); u.i[0] = v.i;
    v.h = __float22bfloat162_rn(make_float2(a.z, a.w)); u.i[1] = v.i;
    v.h = __float22bfloat162_rn(make_float2(b.x, b.y)); u.i[2] = v.i;
    v.h = __float22bfloat162_rn(make_float2(b.z, b.w)); u.i[3] = v.i;
    return u.s8;
}

// Verified layouts (R1..R5 passing): A[m=lane&15][k=(lane>>4)*8+j],
// B[n=lane&15][k=(lane>>4)*8+j], D col=lane&15, row=(lane>>4)*4+reg.
__global__ __launch_bounds__(256) void qlstm_gemm(
    const float* __restrict__ X,
    const float* __restrict__ Wf, const float* __restrict__ Wi,
    const float* __restrict__ Wu, const float* __restrict__ Wo,
    const float* __restrict__ bfv, const float* __restrict__ biv,
    const float* __restrict__ buv, const float* __restrict__ bov,
    float* __restrict__ Z)
{
    const int l   = threadIdx.x & 63;
    const int wid = threadIdx.x >> 6;
    const int lm  = l & 15;
    const int lk  = l >> 4;

    const float* Wg[4] = {Wf, Wi, Wu, Wo};
    const float* Bg[4] = {bfv, biv, buv, bov};

    short8 Bhi[2][8], Blo[2][8];
    float bias[2];
    #pragma unroll
    for (int nt = 0; nt < 2; ++nt) {
        const int c = nt * 16 + lm;                  // col = kq*4 + g
        const float* wrow = Wg[c & 3] + (c >> 2) * DCOMB;
        bias[nt] = Bg[c & 3][c >> 2];
        #pragma unroll
        for (int ks = 0; ks < 8; ++ks) {
            const float* p = wrow + ks * 32 + lk * 8;
            const float4 w0 = *(const float4*)p;
            const float4 w1 = *(const float4*)(p + 4);
            const float wv[8] = {w0.x, w0.y, w0.z, w0.w, w1.x, w1.y, w1.z, w1.w};
            #pragma unroll
            for (int j = 0; j < 8; ++j) {
                const short hi = f2bf(wv[j]);
                Bhi[nt][ks][j] = hi;
                Blo[nt][ks][j] = f2bf(wv[j] - bf2f(hi));
            }
        }
    }

    #pragma unroll
    for (int ch = 0; ch < MCHUNKS; ++ch) {
        const int row0 = (blockIdx.x * MCHUNKS + ch) * 64 + wid * 16;
        const float* xbase = X + (long)(row0 + lm) * DIN + lk * 8;

        float4 xv[16];
        #pragma unroll
        for (int i = 0; i < 16; ++i)
            xv[i] = *(const float4*)(xbase + (i >> 1) * 32 + (i & 1) * 4);

        f32x4 acc0 = (f32x4){bias[0], bias[0], bias[0], bias[0]};
        f32x4 acc1 = (f32x4){bias[1], bias[1], bias[1], bias[1]};
        #pragma unroll
        for (int ks = 0; ks < 8; ++ks) {
            const short8 a = pack8(xv[2 * ks], xv[2 * ks + 1]);
            acc0 = __builtin_amdgcn_mfma_f32_16x16x32_bf16(a, Bhi[0][ks], acc0, 0, 0, 0);
            acc0 = __builtin_amdgcn_mfma_f32_16x16x32_bf16(a, Blo[0][ks], acc0, 0, 0, 0);
            acc1 = __builtin_amdgcn_mfma_f32_16x16x32_bf16(a, Bhi[1][ks], acc1, 0, 0, 0);
            acc1 = __builtin_amdgcn_mfma_f32_16x16x32_bf16(a, Blo[1][ks], acc1, 0, 0, 0);
        }

        #pragma unroll
        for (int r = 0; r < 4; ++r) {
            Z[(long)(row0 + lk * 4 + r) * 32 + lm]      = acc0[r];
            Z[(long)(row0 + lk * 4 + r) * 32 + 16 + lm] = acc1[r];
        }
    }
}

// ------------------------------ kernel 2: scan -----------------------------
// Lane map (NEW): q = 2*kq + hi  (kq = q>>1 qubit, hi = q&1 gate-pair).
// DPP conventions (verified): row_shr:d -> dst[i]=src[i-d], invalid -> old;
// row_ror:s -> dst[i]=src[(i-s) mod 16]; quad_perm ctrl in [0,0xFF].
// With the interleaved map, prefix-product group boundary (kq<d) coincides
// with the 16-lane row edge (q-2d<0), so DPP old=1.0 supplies the identity
// and the per-stage cndmask select is gone.
#define DPP_ROR(V, S) \
    __int_as_float(__builtin_amdgcn_update_dpp(__float_as_int(V), __float_as_int(V), 0x120 | (S), 0xF, 0xF, false))
#define QP(V, CTRL) \
    __int_as_float(__builtin_amdgcn_update_dpp(__float_as_int(V), __float_as_int(V), (CTRL), 0xF, 0xF, false))

// prefix-product stage, shift D lanes (= D/2 qubits); shifted-in value = 1.0
#define PSTG2(A, D) { \
    float s0_ = __int_as_float(__builtin_amdgcn_update_dpp(one_i, __float_as_int(A.x), 0x110 | (D), 0xF, 0xF, false)); \
    float s1_ = __int_as_float(__builtin_amdgcn_update_dpp(one_i, __float_as_int(A.y), 0x110 | (D), 0xF, 0xF, false)); \
    A *= (f32x2){s0_, s1_}; }

#define PF 8   // prefetch ring depth

// grid: 128 blocks x 64 threads = 8192 = 512 batches * 16 lanes
__global__ __launch_bounds__(64, 1) void qlstm_scan(
    const float* __restrict__ Z,
    const float* __restrict__ Wf, const float* __restrict__ Wi,
    const float* __restrict__ Wu, const float* __restrict__ Wo,
    const float* __restrict__ pf, const float* __restrict__ pi_,
    const float* __restrict__ pu, const float* __restrict__ po,
    float* __restrict__ out)
{
    const int tx  = threadIdx.x;
    const int q   = tx & 15;                         // lane-in-batch 0..15
    const int kq  = q >> 1;                          // qubit index
    const int hi  = q & 1;                           // 0: gates (f,i); 1: (u,o)
    const int b   = (blockIdx.x * 64 + tx) >> 4;     // batch 0..511
    const int oidx = b * 8 + kq;
    const int woff = kq * DCOMB + DIN;

    // per-lane gate-pair selection
    const float* WgA = hi ? Wu : Wf;
    const float* WgB = hi ? Wo : Wi;
    f32x2 wp[8];                                     // rotated recurrent weights
    #pragma unroll
    for (int s = 0; s < 8; ++s) {
        const int j = (kq - s) & 7;
        wp[s] = (f32x2){WgA[woff + j], WgB[woff + j]};
    }
    const f32x2 cth = (f32x2){__cosf((hi ? pu : pf)[kq]),
                              __cosf((hi ? po : pi_)[kq])};

    // activation poly: act(x) = k0 + x*(k1 + t*(k2 + t*(k3 + t*k4))), t=x^2
    // comp0: sigmoid (hi=0) / tanh minimax (hi=1); comp1: sigmoid. |x|<=1.
    const float SK1 = 0.25f, SK2 = -0.0208333333f, SK3 = 0.0020833333f,
                SK4 = -0.00021082f;
    const f32x2 k0 = (f32x2){hi ? 0.0f : 0.5f, 0.5f};
    const f32x2 k1 = (f32x2){hi ? 0.9999016f : SK1, SK1};
    const f32x2 k2 = (f32x2){hi ? -0.3310485f : SK2, SK2};
    const f32x2 k3 = (f32x2){hi ? 0.1204423f : SK3, SK3};
    const f32x2 k4 = (f32x2){hi ? -0.0277012f : SK4, SK4};

    const int one_i = __float_as_int(1.0f);

    float hx = 0.0f, cx = 0.0f;
    // per-lane float2 of Z: gates (2*hi, 2*hi+1) of qubit kq
    const float2* __restrict__ Zv2 = (const float2*)Z;
    const int zoff = b * 16 + q;                     // float2 index in a t-slice
    float* __restrict__ outp = out + oidx;

    float2 ring[PF];
    #pragma unroll
    for (int i = 0; i < PF; ++i) ring[i] = Zv2[(i << 13) + zoff];

    for (int t0 = 0; t0 < SEQ; t0 += PF) {
        #pragma unroll
        for (int u = 0; u < PF; ++u) {
            const int t = t0 + u;
            const float2 z2 = ring[u];
            int tn = t + PF; if (tn > SEQ - 1) tn = SEQ - 1;
            ring[u] = Zv2[(tn << 13) + zoff];        // deep prefetch

            // hx rotations (hx pair-duplicated; qubit shift s = lane ror 2s)
            const float h0 = hx;
            const float h1 = DPP_ROR(hx, 2),  h2 = DPP_ROR(hx, 4);
            const float h3 = DPP_ROR(hx, 6),  h4 = DPP_ROR(hx, 8);
            const float h5 = DPP_ROR(hx, 10), h6 = DPP_ROR(hx, 12);
            const float h7 = DPP_ROR(hx, 14);

            // pre-pair = z + hx @ Wh.T (balanced fma tree)
            f32x2 e0 = (f32x2){h0, h0} * wp[0] + (f32x2){h1, h1} * wp[1];
            f32x2 e1 = (f32x2){h2, h2} * wp[2] + (f32x2){h3, h3} * wp[3];
            f32x2 e2 = (f32x2){h4, h4} * wp[4] + (f32x2){h5, h5} * wp[5];
            f32x2 e3 = (f32x2){h6, h6} * wp[6] + (f32x2){h7, h7} * wp[7];
            const f32x2 p = (((f32x2){z2.x, z2.y} + e0) + (e1 + e2)) + e3;

            // qgate: a = cos(pre)*cos(theta), then qubit prefix product
            f32x2 A = (f32x2){__cosf(p.x), __cosf(p.y)} * cth;
            PSTG2(A, 2) PSTG2(A, 4) PSTG2(A, 8)

            // activations via per-lane poly (|A|<=1)
            const f32x2 t2 = A * A;
            f32x2 r = k3 + t2 * k4;
            r = k2 + t2 * r;
            r = k1 + t2 * r;
            const f32x2 P = k0 + A * r;

            // broadcast all 4 gates to both lanes of the pair (quad_perm)
            const float f_all = QP(P.x, 0xA0);       // [0,0,2,2]
            const float u_all = QP(P.x, 0xF5);       // [1,1,3,3]
            const float i_all = QP(P.y, 0xA0);
            const float o_all = QP(P.y, 0xF5);

            // cx = f*cx + i*u   (valid in ALL lanes, pair-duplicated)
            cx = fmaf(f_all, cx, i_all * u_all);

            // tanh(cx) via Pade[5/4] (|cx| <= ~2.1), 1 rcp
            const float tq  = cx * cx;
            const float num = cx * fmaf(tq, fmaf(tq, 1.0f, 105.0f), 945.0f);
            const float den = fmaf(tq, fmaf(tq, 15.0f, 420.0f), 945.0f);
            const float tc  = num * __builtin_amdgcn_rcpf(den);

            // hx = o * tanh(cx) — valid in all lanes, no cross-lane tail
            hx = o_all * tc;

            outp[t << 12] = hx;                      // dup lanes write same bits
        }
    }
    if (hi == 0) {
        out[NROWS * 8 + oidx]        = hx;           // final hx (512,8)
        out[NROWS * 8 + 4096 + oidx] = cx;           // final cx (512,8)
    }
}

// ---------------------------------------------------------------------------
extern "C" void kernel_launch(void* const* d_in, const int* in_sizes, int n_in,
                              void* d_out, int out_size, void* d_ws, size_t ws_size,
                              hipStream_t stream) {
    const float* X   = (const float*)d_in[0];
    const float* Wf  = (const float*)d_in[1];
    const float* bfv = (const float*)d_in[2];
    const float* Wi  = (const float*)d_in[3];
    const float* biv = (const float*)d_in[4];
    const float* Wu  = (const float*)d_in[5];
    const float* buv = (const float*)d_in[6];
    const float* Wo  = (const float*)d_in[7];
    const float* bov = (const float*)d_in[8];
    const float* pf  = (const float*)d_in[9];
    const float* pi_ = (const float*)d_in[10];
    const float* pu  = (const float*)d_in[11];
    const float* po  = (const float*)d_in[12];
    float* out = (float*)d_out;
    float* Z   = (float*)d_ws;   // 131072 * 32 * 4 B = 16.8 MB scratch

    qlstm_gemm<<<NROWS / (64 * MCHUNKS), 256, 0, stream>>>(
        X, Wf, Wi, Wu, Wo, bfv, biv, buv, bov, Z);
    qlstm_scan<<<128, 64, 0, stream>>>(Z, Wf, Wi, Wu, Wo, pf, pi_, pu, po, out);
}

// Round 2
// 254.160 us; speedup vs baseline: 1.0511x; 1.0330x over previous
//
#include <hip/hip_runtime.h>
#include <hip/hip_bf16.h>

// ---------------------------------------------------------------------------
// QLSTM fused: seq=256, batch=512, input=256, H=n_qubits=8.
// ONE kernel, 256 blocks x 512 threads. Block b owns batches {2b, 2b+1}:
//   phase 1: 8 waves MFMA-gemm 512 (t,batch)-rows -> Z in LDS (stride-34 f32)
//            weight bf16 hi/lo fragments staged in LDS (32 KB, ~110 VGPR)
//   phase 2: wave 0 runs the 256-step recurrent scan reading Z from LDS.
// Z never touches HBM; no second launch; no grid-wide sync needed.
// Scan math identical to R1 (verified, absmax 0.0078125).
// ---------------------------------------------------------------------------

#define SEQ   256
#define BATCH 512
#define DIN   256
#define NROWS (SEQ * BATCH)      // 131072
#define DCOMB 264                // 256 + 8
#define ZSTR  34                 // LDS Z row stride in floats (even, 2-way max)

typedef __attribute__((ext_vector_type(8))) short short8;
typedef __attribute__((ext_vector_type(4))) float f32x4;
typedef __attribute__((ext_vector_type(2))) float f32x2;

__device__ __forceinline__ short f2bf(float f) {
    union { __hip_bfloat16 h; short s; } u;
    u.h = __float2bfloat16(f);
    return u.s;
}
__device__ __forceinline__ float bf2f(short s) {
    union { short s; __hip_bfloat16 h; } u;
    u.s = s;
    return __bfloat162float(u.h);
}

__device__ __forceinline__ short8 pack8(float4 a, float4 b) {
    union { short8 s8; int i[4]; } u;
    union { __hip_bfloat162 h; int i; } v;
    v.h = __float22bfloat162_rn(make_float2(a.x, a.y)); u.i[0] = v.i;
    v.h = __float22bfloat162_rn(make_float2(a.z, a.w)); u.i[1] = v.i;
    v.h = __float22bfloat162_rn(make_float2(b.x, b.y)); u.i[2] = v.i;
    v.h = __float22bfloat162_rn(make_float2(b.z, b.w)); u.i[3] = v.i;
    return u.s8;
}

// DPP conventions (verified): row_shr:d -> dst[i]=src[i-d], invalid -> old;
// row_ror:s -> dst[i]=src[(i-s) mod 16]; quad_perm ctrl in [0,0xFF].
#define DPP_ROR(V, S) \
    __int_as_float(__builtin_amdgcn_update_dpp(__float_as_int(V), __float_as_int(V), 0x120 | (S), 0xF, 0xF, false))
#define QP(V, CTRL) \
    __int_as_float(__builtin_amdgcn_update_dpp(__float_as_int(V), __float_as_int(V), (CTRL), 0xF, 0xF, false))
// prefix-product stage, shift D lanes (= D/2 qubits); shifted-in value = 1.0
#define PSTG2(A, D) { \
    float s0_ = __int_as_float(__builtin_amdgcn_update_dpp(one_i, __float_as_int(A.x), 0x110 | (D), 0xF, 0xF, false)); \
    float s1_ = __int_as_float(__builtin_amdgcn_update_dpp(one_i, __float_as_int(A.y), 0x110 | (D), 0xF, 0xF, false)); \
    A *= (f32x2){s0_, s1_}; }

__global__ __launch_bounds__(512, 2) void qlstm_fused(
    const float* __restrict__ X,
    const float* __restrict__ Wf, const float* __restrict__ Wi,
    const float* __restrict__ Wu, const float* __restrict__ Wo,
    const float* __restrict__ bfv, const float* __restrict__ biv,
    const float* __restrict__ buv, const float* __restrict__ bov,
    const float* __restrict__ pf, const float* __restrict__ pi_,
    const float* __restrict__ pu, const float* __restrict__ po,
    float* __restrict__ out)
{
    // [nt(2)][hl(2)][ks(8)][lane(64)] bf16 B-fragments: 2048 * 16 B = 32 KB
    __shared__ short8 Wl[2048];
    // Z: 512 rows (r = 2t + bl) x 32 cols, stride 34 floats = 68 KB
    __shared__ float Zl[512 * ZSTR];

    const int tx  = threadIdx.x;
    const int l   = tx & 63;
    const int wid = tx >> 6;
    const int lm  = l & 15;
    const int lk  = l >> 4;
    const int B0  = blockIdx.x;              // batch pair index

    const float* Wg[4] = {Wf, Wi, Wu, Wo};
    const float* Bg[4] = {bfv, biv, buv, bov};

    // ---- preamble: convert W -> LDS bf16 hi/lo fragments (once per block) ---
    #pragma unroll
    for (int e = 0; e < 4; ++e) {
        const int ent  = tx + e * 512;       // 0..2047
        const int lane = ent & 63;
        const int ks   = (ent >> 6) & 7;
        const int hl   = (ent >> 9) & 1;
        const int nt   = (ent >> 10) & 1;
        const int elm  = lane & 15, elk = lane >> 4;
        const int c    = nt * 16 + elm;      // col = kq*4 + g
        const float* wrow = Wg[c & 3] + (c >> 2) * DCOMB + ks * 32 + elk * 8;
        short8 fr;
        #pragma unroll
        for (int j = 0; j < 8; ++j) {
            const float v = wrow[j];
            const short h16 = f2bf(v);
            fr[j] = hl ? f2bf(v - bf2f(h16)) : h16;
        }
        Wl[ent] = fr;
    }

    // bias per lane (bias of output col = lane's D column)
    float bias0, bias1;
    { const int c0 = lm;      bias0 = Bg[c0 & 3][c0 >> 2];
      const int c1 = 16 + lm; bias1 = Bg[c1 & 3][c1 >> 2]; }

    __syncthreads();

    // ---- phase 1: gemm. 4 passes x 8 waves x 16 rows = 512 local rows ------
    // local row r = 2t + bl;  global X row = t*BATCH + (2*B0 + bl)
    #pragma unroll
    for (int p = 0; p < 4; ++p) {
        const int r0 = p * 128 + wid * 16;
        const int r  = r0 + lm;              // this lane's A-row
        const float* xbase =
            X + ((long)(r >> 1) * BATCH + B0 * 2 + (r & 1)) * DIN + lk * 8;

        float4 xv[16];
        #pragma unroll
        for (int i = 0; i < 16; ++i)
            xv[i] = *(const float4*)(xbase + (i >> 1) * 32 + (i & 1) * 4);

        f32x4 acc0 = (f32x4){bias0, bias0, bias0, bias0};
        f32x4 acc1 = (f32x4){bias1, bias1, bias1, bias1};
        #pragma unroll
        for (int ks = 0; ks < 8; ++ks) {
            const short8 a = pack8(xv[2 * ks], xv[2 * ks + 1]);
            acc0 = __builtin_amdgcn_mfma_f32_16x16x32_bf16(a, Wl[ks * 64 + l],        acc0, 0, 0, 0);
            acc0 = __builtin_amdgcn_mfma_f32_16x16x32_bf16(a, Wl[(8  + ks) * 64 + l], acc0, 0, 0, 0);
            acc1 = __builtin_amdgcn_mfma_f32_16x16x32_bf16(a, Wl[(16 + ks) * 64 + l], acc1, 0, 0, 0);
            acc1 = __builtin_amdgcn_mfma_f32_16x16x32_bf16(a, Wl[(24 + ks) * 64 + l], acc1, 0, 0, 0);
        }

        // D layout: col = lane&15, row = (lane>>4)*4 + reg
        #pragma unroll
        for (int rr = 0; rr < 4; ++rr) {
            Zl[(r0 + lk * 4 + rr) * ZSTR + lm]      = acc0[rr];
            Zl[(r0 + lk * 4 + rr) * ZSTR + 16 + lm] = acc1[rr];
        }
    }
    __syncthreads();

    if (tx >= 64) return;                    // waves 1..7 done

    // ---- phase 2: scan (wave 0). lanes 32-63 mirror lanes 0-31 -------------
    const int q   = tx & 15;                 // lane-in-batch 0..15
    const int kq  = q >> 1;                  // qubit index
    const int hi  = q & 1;                   // 0: gates (f,i); 1: (u,o)
    const int bl  = (tx >> 4) & 1;           // batch-in-pair (mirrored 32-63)
    const int b   = B0 * 2 + bl;
    const int oidx = b * 8 + kq;
    const int woff = kq * DCOMB + DIN;

    const float* WgA = hi ? Wu : Wf;
    const float* WgB = hi ? Wo : Wi;
    f32x2 wp[8];                             // rotated recurrent weights
    #pragma unroll
    for (int s = 0; s < 8; ++s) {
        const int j = (kq - s) & 7;
        wp[s] = (f32x2){WgA[woff + j], WgB[woff + j]};
    }
    const f32x2 cth = (f32x2){__cosf((hi ? pu : pf)[kq]),
                              __cosf((hi ? po : pi_)[kq])};

    // activation poly: act(x) = k0 + x*(k1 + t*(k2 + t*(k3 + t*k4))), t=x^2
    const float SK1 = 0.25f, SK2 = -0.0208333333f, SK3 = 0.0020833333f,
                SK4 = -0.00021082f;
    const f32x2 k0 = (f32x2){hi ? 0.0f : 0.5f, 0.5f};
    const f32x2 k1 = (f32x2){hi ? 0.9999016f : SK1, SK1};
    const f32x2 k2 = (f32x2){hi ? -0.3310485f : SK2, SK2};
    const f32x2 k3 = (f32x2){hi ? 0.1204423f : SK3, SK3};
    const f32x2 k4 = (f32x2){hi ? -0.0277012f : SK4, SK4};

    const int one_i = __float_as_int(1.0f);

    float hx = 0.0f, cx = 0.0f;
    const int zbase = bl * ZSTR + 2 * q;     // row r = 2t+bl, float2 at col 2q
    float* __restrict__ outp = out + oidx;

    // 2-deep LDS prefetch ring
    f32x2 ring0 = *(const f32x2*)&Zl[zbase];
    f32x2 ring1 = *(const f32x2*)&Zl[2 * ZSTR + zbase];

    #pragma unroll 4
    for (int t = 0; t < SEQ; ++t) {
        const f32x2 z2 = ring0;
        ring0 = ring1;
        int tn = t + 2; if (tn > SEQ - 1) tn = SEQ - 1;
        ring1 = *(const f32x2*)&Zl[tn * (2 * ZSTR) + zbase];

        // hx rotations (hx pair-duplicated; qubit shift s = lane ror 2s)
        const float h0 = hx;
        const float h1 = DPP_ROR(hx, 2),  h2 = DPP_ROR(hx, 4);
        const float h3 = DPP_ROR(hx, 6),  h4 = DPP_ROR(hx, 8);
        const float h5 = DPP_ROR(hx, 10), h6 = DPP_ROR(hx, 12);
        const float h7 = DPP_ROR(hx, 14);

        // pre-pair = z + hx @ Wh.T (balanced fma tree)
        f32x2 e0 = (f32x2){h0, h0} * wp[0] + (f32x2){h1, h1} * wp[1];
        f32x2 e1 = (f32x2){h2, h2} * wp[2] + (f32x2){h3, h3} * wp[3];
        f32x2 e2 = (f32x2){h4, h4} * wp[4] + (f32x2){h5, h5} * wp[5];
        f32x2 e3 = (f32x2){h6, h6} * wp[6] + (f32x2){h7, h7} * wp[7];
        const f32x2 p = ((z2 + e0) + (e1 + e2)) + e3;

        // qgate: a = cos(pre)*cos(theta), then qubit prefix product
        f32x2 A = (f32x2){__cosf(p.x), __cosf(p.y)} * cth;
        PSTG2(A, 2) PSTG2(A, 4) PSTG2(A, 8)

        // activations via per-lane poly (|A|<=1)
        const f32x2 t2 = A * A;
        f32x2 rr = k3 + t2 * k4;
        rr = k2 + t2 * rr;
        rr = k1 + t2 * rr;
        const f32x2 P = k0 + A * rr;

        // broadcast all 4 gates to both lanes of the pair (quad_perm)
        const float f_all = QP(P.x, 0xA0);   // [0,0,2,2]
        const float u_all = QP(P.x, 0xF5);   // [1,1,3,3]
        const float i_all = QP(P.y, 0xA0);
        const float o_all = QP(P.y, 0xF5);

        // cx = f*cx + i*u   (valid in ALL lanes, pair-duplicated)
        cx = fmaf(f_all, cx, i_all * u_all);

        // tanh(cx) via Pade[5/4] (|cx| <= ~2.1), 1 rcp
        const float tq  = cx * cx;
        const float num = cx * fmaf(tq, fmaf(tq, 1.0f, 105.0f), 945.0f);
        const float den = fmaf(tq, fmaf(tq, 15.0f, 420.0f), 945.0f);
        const float tc  = num * __builtin_amdgcn_rcpf(den);

        // hx = o * tanh(cx) — valid in all lanes
        hx = o_all * tc;

        outp[t << 12] = hx;                  // dup lanes write same bits
    }
    if (hi == 0 && tx < 32) {
        out[NROWS * 8 + oidx]        = hx;   // final hx (512,8)
        out[NROWS * 8 + 4096 + oidx] = cx;   // final cx (512,8)
    }
}

// ---------------------------------------------------------------------------
extern "C" void kernel_launch(void* const* d_in, const int* in_sizes, int n_in,
                              void* d_out, int out_size, void* d_ws, size_t ws_size,
                              hipStream_t stream) {
    const float* X   = (const float*)d_in[0];
    const float* Wf  = (const float*)d_in[1];
    const float* bfv = (const float*)d_in[2];
    const float* Wi  = (const float*)d_in[3];
    const float* biv = (const float*)d_in[4];
    const float* Wu  = (const float*)d_in[5];
    const float* buv = (const float*)d_in[6];
    const float* Wo  = (const float*)d_in[7];
    const float* bov = (const float*)d_in[8];
    const float* pf  = (const float*)d_in[9];
    const float* pi_ = (const float*)d_in[10];
    const float* pu  = (const float*)d_in[11];
    const float* po  = (const float*)d_in[12];
    float* out = (float*)d_out;
    (void)d_ws; (void)ws_size;               // workspace no longer needed

    qlstm_fused<<<512 / 2, 512, 0, stream>>>(
        X, Wf, Wi, Wu, Wo, bfv, biv, buv, bov, pf, pi_, pu, po, out);
}

// Round 3
// 251.991 us; speedup vs baseline: 1.0602x; 1.0086x over previous
//
#include <hip/hip_runtime.h>
#include <hip/hip_bf16.h>

// ---------------------------------------------------------------------------
// QLSTM fused: seq=256, batch=512, input=256, H=n_qubits=8.
// ONE kernel, 256 blocks x 512 threads. Block b owns batches {2b, 2b+1}:
//   phase 1: 8 waves MFMA-gemm 512 (t,batch)-rows -> Z in LDS (stride-34 f32)
//   phase 2: wave 0 runs the 256-step scan from LDS; hx history buffered in
//            LDS (no per-step global stores); waves 1..7 wait at barrier.
//   phase 3: all 8 waves bulk-dump the 16 KB hx history with float4 stores.
// Z and per-step hx never touch HBM. Scan math identical to R1/R2 (verified).
// ---------------------------------------------------------------------------

#define SEQ   256
#define BATCH 512
#define DIN   256
#define NROWS (SEQ * BATCH)      // 131072
#define DCOMB 264                // 256 + 8
#define ZSTR  34                 // LDS Z row stride in floats (even, 2-way max)

typedef __attribute__((ext_vector_type(8))) short short8;
typedef __attribute__((ext_vector_type(4))) float f32x4;
typedef __attribute__((ext_vector_type(2))) float f32x2;

__device__ __forceinline__ short f2bf(float f) {
    union { __hip_bfloat16 h; short s; } u;
    u.h = __float2bfloat16(f);
    return u.s;
}
__device__ __forceinline__ float bf2f(short s) {
    union { short s; __hip_bfloat16 h; } u;
    u.s = s;
    return __bfloat162float(u.h);
}

__device__ __forceinline__ short8 pack8(float4 a, float4 b) {
    union { short8 s8; int i[4]; } u;
    union { __hip_bfloat162 h; int i; } v;
    v.h = __float22bfloat162_rn(make_float2(a.x, a.y)); u.i[0] = v.i;
    v.h = __float22bfloat162_rn(make_float2(a.z, a.w)); u.i[1] = v.i;
    v.h = __float22bfloat162_rn(make_float2(b.x, b.y)); u.i[2] = v.i;
    v.h = __float22bfloat162_rn(make_float2(b.z, b.w)); u.i[3] = v.i;
    return u.s8;
}

// DPP conventions (verified): row_shr:d -> dst[i]=src[i-d], invalid -> old;
// row_ror:s -> dst[i]=src[(i-s) mod 16]; quad_perm ctrl in [0,0xFF].
#define DPP_ROR(V, S) \
    __int_as_float(__builtin_amdgcn_update_dpp(__float_as_int(V), __float_as_int(V), 0x120 | (S), 0xF, 0xF, false))
#define QP(V, CTRL) \
    __int_as_float(__builtin_amdgcn_update_dpp(__float_as_int(V), __float_as_int(V), (CTRL), 0xF, 0xF, false))
// prefix-product stage, shift D lanes (= D/2 qubits); shifted-in value = 1.0
#define PSTG2(A, D) { \
    float s0_ = __int_as_float(__builtin_amdgcn_update_dpp(one_i, __float_as_int(A.x), 0x110 | (D), 0xF, 0xF, false)); \
    float s1_ = __int_as_float(__builtin_amdgcn_update_dpp(one_i, __float_as_int(A.y), 0x110 | (D), 0xF, 0xF, false)); \
    A *= (f32x2){s0_, s1_}; }

__global__ __launch_bounds__(512, 2) void qlstm_fused(
    const float* __restrict__ X,
    const float* __restrict__ Wf, const float* __restrict__ Wi,
    const float* __restrict__ Wu, const float* __restrict__ Wo,
    const float* __restrict__ bfv, const float* __restrict__ biv,
    const float* __restrict__ buv, const float* __restrict__ bov,
    const float* __restrict__ pf, const float* __restrict__ pi_,
    const float* __restrict__ pu, const float* __restrict__ po,
    float* __restrict__ out)
{
    // [nt(2)][hl(2)][ks(8)][lane(64)] bf16 B-fragments: 2048 * 16 B = 32 KB
    __shared__ short8 Wl[2048];
    // Z: 512 rows (r = 2t + bl) x 32 cols, stride 34; +4 pad rows for the
    // clamp-free ring prefetch (over-read garbage is never consumed). 68.5 KB
    __shared__ float Zl[516 * ZSTR];
    // hx history: [t][bl*8+kq] = 256*16 floats = 16 KB
    __shared__ float Hl[SEQ * 16];

    const int tx  = threadIdx.x;
    const int l   = tx & 63;
    const int wid = tx >> 6;
    const int lm  = l & 15;
    const int lk  = l >> 4;
    const int B0  = blockIdx.x;              // batch pair index

    const float* Wg[4] = {Wf, Wi, Wu, Wo};
    const float* Bg[4] = {bfv, biv, buv, bov};

    // ---- preamble: convert W -> LDS bf16 hi/lo fragments (once per block) ---
    #pragma unroll
    for (int e = 0; e < 4; ++e) {
        const int ent  = tx + e * 512;       // 0..2047
        const int lane = ent & 63;
        const int ks   = (ent >> 6) & 7;
        const int hl   = (ent >> 9) & 1;
        const int nt   = (ent >> 10) & 1;
        const int elm  = lane & 15, elk = lane >> 4;
        const int c    = nt * 16 + elm;      // col = kq*4 + g
        const float* wrow = Wg[c & 3] + (c >> 2) * DCOMB + ks * 32 + elk * 8;
        short8 fr;
        #pragma unroll
        for (int j = 0; j < 8; ++j) {
            const float v = wrow[j];
            const short h16 = f2bf(v);
            fr[j] = hl ? f2bf(v - bf2f(h16)) : h16;
        }
        Wl[ent] = fr;
    }

    // bias per lane (bias of output col = lane's D column)
    float bias0, bias1;
    { const int c0 = lm;      bias0 = Bg[c0 & 3][c0 >> 2];
      const int c1 = 16 + lm; bias1 = Bg[c1 & 3][c1 >> 2]; }

    __syncthreads();

    // ---- phase 1: gemm. 4 passes x 8 waves x 16 rows = 512 local rows ------
    // local row r = 2t + bl;  global X row = t*BATCH + (2*B0 + bl)
    #pragma unroll
    for (int p = 0; p < 4; ++p) {
        const int r0 = p * 128 + wid * 16;
        const int r  = r0 + lm;              // this lane's A-row
        const float* xbase =
            X + ((long)(r >> 1) * BATCH + B0 * 2 + (r & 1)) * DIN + lk * 8;

        float4 xv[16];
        #pragma unroll
        for (int i = 0; i < 16; ++i)
            xv[i] = *(const float4*)(xbase + (i >> 1) * 32 + (i & 1) * 4);

        f32x4 acc0 = (f32x4){bias0, bias0, bias0, bias0};
        f32x4 acc1 = (f32x4){bias1, bias1, bias1, bias1};
        #pragma unroll
        for (int ks = 0; ks < 8; ++ks) {
            const short8 a = pack8(xv[2 * ks], xv[2 * ks + 1]);
            acc0 = __builtin_amdgcn_mfma_f32_16x16x32_bf16(a, Wl[ks * 64 + l],        acc0, 0, 0, 0);
            acc0 = __builtin_amdgcn_mfma_f32_16x16x32_bf16(a, Wl[(8  + ks) * 64 + l], acc0, 0, 0, 0);
            acc1 = __builtin_amdgcn_mfma_f32_16x16x32_bf16(a, Wl[(16 + ks) * 64 + l], acc1, 0, 0, 0);
            acc1 = __builtin_amdgcn_mfma_f32_16x16x32_bf16(a, Wl[(24 + ks) * 64 + l], acc1, 0, 0, 0);
        }

        // D layout: col = lane&15, row = (lane>>4)*4 + reg
        #pragma unroll
        for (int rr = 0; rr < 4; ++rr) {
            Zl[(r0 + lk * 4 + rr) * ZSTR + lm]      = acc0[rr];
            Zl[(r0 + lk * 4 + rr) * ZSTR + 16 + lm] = acc1[rr];
        }
    }
    __syncthreads();

    // ---- phase 2: scan (wave 0 only; waves 1..7 wait at the barrier) -------
    if (tx < 64) {
        const int q   = tx & 15;             // lane-in-batch 0..15
        const int kq  = q >> 1;              // qubit index
        const int hi  = q & 1;               // 0: gates (f,i); 1: (u,o)
        const int bl  = (tx >> 4) & 1;       // batch-in-pair (mirrored 32-63)
        const int b   = B0 * 2 + bl;
        const int oidx = b * 8 + kq;
        const int woff = kq * DCOMB + DIN;

        const float* WgA = hi ? Wu : Wf;
        const float* WgB = hi ? Wo : Wi;
        f32x2 wp[8];                         // rotated recurrent weights
        #pragma unroll
        for (int s = 0; s < 8; ++s) {
            const int j = (kq - s) & 7;
            wp[s] = (f32x2){WgA[woff + j], WgB[woff + j]};
        }
        const f32x2 cth = (f32x2){__cosf((hi ? pu : pf)[kq]),
                                  __cosf((hi ? po : pi_)[kq])};

        // activation poly: act(x) = k0 + x*(k1 + t*(k2 + t*(k3 + t*k4))), t=x^2
        const float SK1 = 0.25f, SK2 = -0.0208333333f, SK3 = 0.0020833333f,
                    SK4 = -0.00021082f;
        const f32x2 k0 = (f32x2){hi ? 0.0f : 0.5f, 0.5f};
        const f32x2 k1 = (f32x2){hi ? 0.9999016f : SK1, SK1};
        const f32x2 k2 = (f32x2){hi ? -0.3310485f : SK2, SK2};
        const f32x2 k3 = (f32x2){hi ? 0.1204423f : SK3, SK3};
        const f32x2 k4 = (f32x2){hi ? -0.0277012f : SK4, SK4};

        const int one_i = __float_as_int(1.0f);

        float hx = 0.0f, cx = 0.0f;
        const int zbase = bl * ZSTR + 2 * q; // row r = 2t+bl, float2 at col 2q
        float* __restrict__ hlp = Hl + bl * 8 + kq;

        // 2-deep LDS prefetch ring (no clamp; Zl padded, over-read unused)
        f32x2 ring0 = *(const f32x2*)&Zl[zbase];
        f32x2 ring1 = *(const f32x2*)&Zl[2 * ZSTR + zbase];

        #pragma unroll 8
        for (int t = 0; t < SEQ; ++t) {
            const f32x2 z2 = ring0;
            ring0 = ring1;
            ring1 = *(const f32x2*)&Zl[(t + 2) * (2 * ZSTR) + zbase];

            // hx rotations (hx pair-duplicated; qubit shift s = lane ror 2s)
            const float h0 = hx;
            const float h1 = DPP_ROR(hx, 2),  h2 = DPP_ROR(hx, 4);
            const float h3 = DPP_ROR(hx, 6),  h4 = DPP_ROR(hx, 8);
            const float h5 = DPP_ROR(hx, 10), h6 = DPP_ROR(hx, 12);
            const float h7 = DPP_ROR(hx, 14);

            // pre-pair = z + hx @ Wh.T (balanced fma tree)
            f32x2 e0 = (f32x2){h0, h0} * wp[0] + (f32x2){h1, h1} * wp[1];
            f32x2 e1 = (f32x2){h2, h2} * wp[2] + (f32x2){h3, h3} * wp[3];
            f32x2 e2 = (f32x2){h4, h4} * wp[4] + (f32x2){h5, h5} * wp[5];
            f32x2 e3 = (f32x2){h6, h6} * wp[6] + (f32x2){h7, h7} * wp[7];
            const f32x2 p = ((z2 + e0) + (e1 + e2)) + e3;

            // qgate: a = cos(pre)*cos(theta), then qubit prefix product
            f32x2 A = (f32x2){__cosf(p.x), __cosf(p.y)} * cth;
            PSTG2(A, 2) PSTG2(A, 4) PSTG2(A, 8)

            // activations via per-lane poly (|A|<=1)
            const f32x2 t2 = A * A;
            f32x2 rr = k3 + t2 * k4;
            rr = k2 + t2 * rr;
            rr = k1 + t2 * rr;
            const f32x2 P = k0 + A * rr;

            // broadcast all 4 gates to both lanes of the pair (quad_perm)
            const float f_all = QP(P.x, 0xA0);   // [0,0,2,2]
            const float u_all = QP(P.x, 0xF5);   // [1,1,3,3]
            const float i_all = QP(P.y, 0xA0);
            const float o_all = QP(P.y, 0xF5);

            // cx = f*cx + i*u   (valid in ALL lanes, pair-duplicated)
            cx = fmaf(f_all, cx, i_all * u_all);

            // tanh(cx) via Pade[5/4] (|cx| <= ~2.1), 1 rcp
            const float tq  = cx * cx;
            const float num = cx * fmaf(tq, fmaf(tq, 1.0f, 105.0f), 945.0f);
            const float den = fmaf(tq, fmaf(tq, 15.0f, 420.0f), 945.0f);
            const float tc  = num * __builtin_amdgcn_rcpf(den);

            // hx = o * tanh(cx) — valid in all lanes
            hx = o_all * tc;

            hlp[t * 16] = hx;                // LDS history (dup lanes same bits)
        }
        if (hi == 0 && tx < 32) {
            out[NROWS * 8 + oidx]        = hx;   // final hx (512,8)
            out[NROWS * 8 + 4096 + oidx] = cx;   // final cx (512,8)
        }
    }
    __syncthreads();

    // ---- phase 3: bulk dump hx history (all 8 waves, float4 stores) --------
    {
        const int f0 = tx * 8;               // 512 threads x 8 floats = 4 KB*4
        const int t  = f0 >> 4;
        const int c  = f0 & 15;              // 0 or 8
        const float4* src = (const float4*)&Hl[f0];
        float4* dst = (float4*)(out + (long)t * (BATCH * 8) + B0 * 16 + c);
        dst[0] = src[0];
        dst[1] = src[1];
    }
}

// ---------------------------------------------------------------------------
extern "C" void kernel_launch(void* const* d_in, const int* in_sizes, int n_in,
                              void* d_out, int out_size, void* d_ws, size_t ws_size,
                              hipStream_t stream) {
    const float* X   = (const float*)d_in[0];
    const float* Wf  = (const float*)d_in[1];
    const float* bfv = (const float*)d_in[2];
    const float* Wi  = (const float*)d_in[3];
    const float* biv = (const float*)d_in[4];
    const float* Wu  = (const float*)d_in[5];
    const float* buv = (const float*)d_in[6];
    const float* Wo  = (const float*)d_in[7];
    const float* bov = (const float*)d_in[8];
    const float* pf  = (const float*)d_in[9];
    const float* pi_ = (const float*)d_in[10];
    const float* pu  = (const float*)d_in[11];
    const float* po  = (const float*)d_in[12];
    float* out = (float*)d_out;
    (void)d_ws; (void)ws_size;               // workspace not needed

    qlstm_fused<<<BATCH / 2, 512, 0, stream>>>(
        X, Wf, Wi, Wu, Wo, bfv, biv, buv, bov, pf, pi_, pu, po, out);
}

// Round 4
// 249.887 us; speedup vs baseline: 1.0691x; 1.0084x over previous
//
#include <hip/hip_runtime.h>
#include <hip/hip_bf16.h>

// ---------------------------------------------------------------------------
// QLSTM fused: seq=256, batch=512, input=256, H=n_qubits=8.
// ONE kernel, 256 blocks x 512 threads. Block b owns batches {2b, 2b+1}:
//   phase 1: 8 waves MFMA-gemm 512 (t,batch)-rows -> Zt in LDS, TRANSPOSED
//            to [ (bl,q) ][ t ][ comp ] so scan reads are contiguous-in-t.
//   phase 2: wave 0 runs the 256-step scan; Z read as ds_read_b128 chunks
//            (4 per 8 steps, double-buffered 1 body ahead); hx history kept
//            in registers and flushed as 2x ds_write_b128 per 8 steps.
//   phase 3: all 8 waves gather-transpose the history and bulk-dump float4s.
// Scan arithmetic identical to R1..R3 (verified, absmax 0.0078125).
// ---------------------------------------------------------------------------

#define SEQ   256
#define BATCH 512
#define DIN   256
#define NROWS (SEQ * BATCH)      // 131072
#define DCOMB 264                // 256 + 8
#define ZTSTR 514                // floats per (bl,q) stream: 512 + 2 pad
#define HLSTR 260                // floats per c-row of history: 256 + 4 pad

typedef __attribute__((ext_vector_type(8))) short short8;
typedef __attribute__((ext_vector_type(4))) float f32x4;
typedef __attribute__((ext_vector_type(2))) float f32x2;

__device__ __forceinline__ short f2bf(float f) {
    union { __hip_bfloat16 h; short s; } u;
    u.h = __float2bfloat16(f);
    return u.s;
}
__device__ __forceinline__ float bf2f(short s) {
    union { short s; __hip_bfloat16 h; } u;
    u.s = s;
    return __bfloat162float(u.h);
}

__device__ __forceinline__ short8 pack8(float4 a, float4 b) {
    union { short8 s8; int i[4]; } u;
    union { __hip_bfloat162 h; int i; } v;
    v.h = __float22bfloat162_rn(make_float2(a.x, a.y)); u.i[0] = v.i;
    v.h = __float22bfloat162_rn(make_float2(a.z, a.w)); u.i[1] = v.i;
    v.h = __float22bfloat162_rn(make_float2(b.x, b.y)); u.i[2] = v.i;
    v.h = __float22bfloat162_rn(make_float2(b.z, b.w)); u.i[3] = v.i;
    return u.s8;
}

// DPP conventions (verified): row_shr:d -> dst[i]=src[i-d], invalid -> old;
// row_ror:s -> dst[i]=src[(i-s) mod 16]; quad_perm ctrl in [0,0xFF].
#define DPP_ROR(V, S) \
    __int_as_float(__builtin_amdgcn_update_dpp(__float_as_int(V), __float_as_int(V), 0x120 | (S), 0xF, 0xF, false))
#define QP(V, CTRL) \
    __int_as_float(__builtin_amdgcn_update_dpp(__float_as_int(V), __float_as_int(V), (CTRL), 0xF, 0xF, false))
// prefix-product stage, shift D lanes (= D/2 qubits); shifted-in value = 1.0
#define PSTG2(A, D) { \
    float s0_ = __int_as_float(__builtin_amdgcn_update_dpp(one_i, __float_as_int(A.x), 0x110 | (D), 0xF, 0xF, false)); \
    float s1_ = __int_as_float(__builtin_amdgcn_update_dpp(one_i, __float_as_int(A.y), 0x110 | (D), 0xF, 0xF, false)); \
    A *= (f32x2){s0_, s1_}; }

// one 8-step scan body: consume ZC (chunk T0), prefetch ZN (chunk T0+8),
// flush hx history for steps T0..T0+7. All indices static after inlining.
__device__ __forceinline__ void scan_body8(
    int T0, const float* __restrict__ zrow, float* __restrict__ hlrow,
    bool writer, f32x4 (&ZC)[4], f32x4 (&ZN)[4],
    float& hx, float& cx,
    const f32x2 (&wp)[8], const f32x2 cth,
    const f32x2 k0, const f32x2 k1, const f32x2 k2, const f32x2 k3,
    const f32x2 k4, const int one_i)
{
    // prefetch next chunk (body-length chain hides ds latency)
    #pragma unroll
    for (int j = 0; j < 4; ++j)
        ZN[j] = *(const f32x4*)&zrow[(T0 + 8) * 2 + j * 4];

    float hxh[8];
    #pragma unroll
    for (int u = 0; u < 8; ++u) {
        const f32x2 z2 = (f32x2){ ZC[u >> 1][(u & 1) * 2],
                                  ZC[u >> 1][(u & 1) * 2 + 1] };

        // hx rotations (hx pair-duplicated; qubit shift s = lane ror 2s)
        const float h0 = hx;
        const float h1 = DPP_ROR(hx, 2),  h2 = DPP_ROR(hx, 4);
        const float h3 = DPP_ROR(hx, 6),  h4 = DPP_ROR(hx, 8);
        const float h5 = DPP_ROR(hx, 10), h6 = DPP_ROR(hx, 12);
        const float h7 = DPP_ROR(hx, 14);

        // pre-pair = z + hx @ Wh.T (balanced fma tree)
        f32x2 e0 = (f32x2){h0, h0} * wp[0] + (f32x2){h1, h1} * wp[1];
        f32x2 e1 = (f32x2){h2, h2} * wp[2] + (f32x2){h3, h3} * wp[3];
        f32x2 e2 = (f32x2){h4, h4} * wp[4] + (f32x2){h5, h5} * wp[5];
        f32x2 e3 = (f32x2){h6, h6} * wp[6] + (f32x2){h7, h7} * wp[7];
        const f32x2 p = ((z2 + e0) + (e1 + e2)) + e3;

        // qgate: a = cos(pre)*cos(theta), then qubit prefix product
        f32x2 A = (f32x2){__cosf(p.x), __cosf(p.y)} * cth;
        PSTG2(A, 2) PSTG2(A, 4) PSTG2(A, 8)

        // activations via per-lane poly (|A|<=1)
        const f32x2 t2 = A * A;
        f32x2 rr = k3 + t2 * k4;
        rr = k2 + t2 * rr;
        rr = k1 + t2 * rr;
        const f32x2 P = k0 + A * rr;

        // broadcast all 4 gates to both lanes of the pair (quad_perm)
        const float f_all = QP(P.x, 0xA0);   // [0,0,2,2]
        const float u_all = QP(P.x, 0xF5);   // [1,1,3,3]
        const float i_all = QP(P.y, 0xA0);
        const float o_all = QP(P.y, 0xF5);

        // cx = f*cx + i*u   (valid in ALL lanes, pair-duplicated)
        cx = fmaf(f_all, cx, i_all * u_all);

        // tanh(cx) via Pade[5/4] (|cx| <= ~2.1), 1 rcp
        const float tq  = cx * cx;
        const float num = cx * fmaf(tq, fmaf(tq, 1.0f, 105.0f), 945.0f);
        const float den = fmaf(tq, fmaf(tq, 15.0f, 420.0f), 945.0f);
        const float tc  = num * __builtin_amdgcn_rcpf(den);

        // hx = o * tanh(cx) — valid in all lanes
        hx = o_all * tc;
        hxh[u] = hx;
    }

    if (writer) {
        *(f32x4*)&hlrow[T0]     = (f32x4){hxh[0], hxh[1], hxh[2], hxh[3]};
        *(f32x4*)&hlrow[T0 + 4] = (f32x4){hxh[4], hxh[5], hxh[6], hxh[7]};
    }
}

__global__ __launch_bounds__(512, 2) void qlstm_fused(
    const float* __restrict__ X,
    const float* __restrict__ Wf, const float* __restrict__ Wi,
    const float* __restrict__ Wu, const float* __restrict__ Wo,
    const float* __restrict__ bfv, const float* __restrict__ biv,
    const float* __restrict__ buv, const float* __restrict__ bov,
    const float* __restrict__ pf, const float* __restrict__ pi_,
    const float* __restrict__ pu, const float* __restrict__ po,
    float* __restrict__ out)
{
    // [nt(2)][hl(2)][ks(8)][lane(64)] bf16 B-fragments: 2048 * 16 B = 32 KB
    __shared__ short8 Wl[2048];
    // Zt transposed: stream per (bl,q): [bl*16+q][t*2+comp], stride 514,
    // +16 tail pad for the final body's harmless over-prefetch. 64.3 KB
    __shared__ float Zt[32 * ZTSTR + 16];
    // hx history: [c = bl*8+kq][t], stride 260. 16.25 KB
    __shared__ float Hl2[16 * HLSTR];

    const int tx  = threadIdx.x;
    const int l   = tx & 63;
    const int wid = tx >> 6;
    const int lm  = l & 15;
    const int lk  = l >> 4;
    const int B0  = blockIdx.x;              // batch pair index

    const float* Wg[4] = {Wf, Wi, Wu, Wo};
    const float* Bg[4] = {bfv, biv, buv, bov};

    // ---- preamble: convert W -> LDS bf16 hi/lo fragments (once per block) ---
    #pragma unroll
    for (int e = 0; e < 4; ++e) {
        const int ent  = tx + e * 512;       // 0..2047
        const int lane = ent & 63;
        const int ks   = (ent >> 6) & 7;
        const int hl   = (ent >> 9) & 1;
        const int nt   = (ent >> 10) & 1;
        const int elm  = lane & 15, elk = lane >> 4;
        const int c    = nt * 16 + elm;      // col = kq*4 + g
        const float* wrow = Wg[c & 3] + (c >> 2) * DCOMB + ks * 32 + elk * 8;
        short8 fr;
        #pragma unroll
        for (int j = 0; j < 8; ++j) {
            const float v = wrow[j];
            const short h16 = f2bf(v);
            fr[j] = hl ? f2bf(v - bf2f(h16)) : h16;
        }
        Wl[ent] = fr;
    }

    // bias per lane (bias of output col = lane's D column)
    float bias0, bias1;
    { const int c0 = lm;      bias0 = Bg[c0 & 3][c0 >> 2];
      const int c1 = 16 + lm; bias1 = Bg[c1 & 3][c1 >> 2]; }

    __syncthreads();

    // ---- phase 1: gemm. 4 passes x 8 waves x 16 rows = 512 local rows ------
    // local row r = 2t + bl;  global X row = t*BATCH + (2*B0 + bl)
    #pragma unroll
    for (int p = 0; p < 4; ++p) {
        const int r0 = p * 128 + wid * 16;
        const int r  = r0 + lm;              // this lane's A-row
        const float* xbase =
            X + ((long)(r >> 1) * BATCH + B0 * 2 + (r & 1)) * DIN + lk * 8;

        float4 xv[16];
        #pragma unroll
        for (int i = 0; i < 16; ++i)
            xv[i] = *(const float4*)(xbase + (i >> 1) * 32 + (i & 1) * 4);

        f32x4 acc0 = (f32x4){bias0, bias0, bias0, bias0};
        f32x4 acc1 = (f32x4){bias1, bias1, bias1, bias1};
        #pragma unroll
        for (int ks = 0; ks < 8; ++ks) {
            const short8 a = pack8(xv[2 * ks], xv[2 * ks + 1]);
            acc0 = __builtin_amdgcn_mfma_f32_16x16x32_bf16(a, Wl[ks * 64 + l],        acc0, 0, 0, 0);
            acc0 = __builtin_amdgcn_mfma_f32_16x16x32_bf16(a, Wl[(8  + ks) * 64 + l], acc0, 0, 0, 0);
            acc1 = __builtin_amdgcn_mfma_f32_16x16x32_bf16(a, Wl[(16 + ks) * 64 + l], acc1, 0, 0, 0);
            acc1 = __builtin_amdgcn_mfma_f32_16x16x32_bf16(a, Wl[(24 + ks) * 64 + l], acc1, 0, 0, 0);
        }

        // D layout: col = lane&15, row = (lane>>4)*4 + reg. Scatter into the
        // transposed stream: element (r, c) -> Zt[(r&1)*16 + (c>>1)][ (r>>1)*2 + (c&1) ]
        #pragma unroll
        for (int rr = 0; rr < 4; ++rr) {
            const int rw = r0 + lk * 4 + rr;
            const int tt = rw >> 1, blw = rw & 1;
            Zt[(blw * 16 + (lm >> 1)) * ZTSTR + tt * 2 + (lm & 1)]     = acc0[rr];
            Zt[(blw * 16 + 8 + (lm >> 1)) * ZTSTR + tt * 2 + (lm & 1)] = acc1[rr];
        }
    }
    __syncthreads();

    // ---- phase 2: scan (wave 0 only; waves 1..7 wait at the barrier) -------
    if (tx < 64) {
        const int q   = tx & 15;             // lane-in-batch 0..15
        const int kq  = q >> 1;              // qubit index
        const int hi  = q & 1;               // 0: gates (f,i); 1: (u,o)
        const int bl  = (tx >> 4) & 1;       // batch-in-pair (mirrored 32-63)
        const int b   = B0 * 2 + bl;
        const int oidx = b * 8 + kq;
        const int woff = kq * DCOMB + DIN;

        const float* WgA = hi ? Wu : Wf;
        const float* WgB = hi ? Wo : Wi;
        f32x2 wp[8];                         // rotated recurrent weights
        #pragma unroll
        for (int s = 0; s < 8; ++s) {
            const int j = (kq - s) & 7;
            wp[s] = (f32x2){WgA[woff + j], WgB[woff + j]};
        }
        const f32x2 cth = (f32x2){__cosf((hi ? pu : pf)[kq]),
                                  __cosf((hi ? po : pi_)[kq])};

        // activation poly: act(x) = k0 + x*(k1 + t*(k2 + t*(k3 + t*k4))), t=x^2
        const float SK1 = 0.25f, SK2 = -0.0208333333f, SK3 = 0.0020833333f,
                    SK4 = -0.00021082f;
        const f32x2 k0 = (f32x2){hi ? 0.0f : 0.5f, 0.5f};
        const f32x2 k1 = (f32x2){hi ? 0.9999016f : SK1, SK1};
        const f32x2 k2 = (f32x2){hi ? -0.3310485f : SK2, SK2};
        const f32x2 k3 = (f32x2){hi ? 0.1204423f : SK3, SK3};
        const f32x2 k4 = (f32x2){hi ? -0.0277012f : SK4, SK4};

        const int one_i = __float_as_int(1.0f);

        float hx = 0.0f, cx = 0.0f;
        const float* __restrict__ zrow = &Zt[(bl * 16 + q) * ZTSTR];
        float* __restrict__ hlrow = &Hl2[(bl * 8 + kq) * HLSTR];
        const bool writer = (hi == 0) && (tx < 32);

        f32x4 zbA[4], zbB[4];
        #pragma unroll
        for (int j = 0; j < 4; ++j) zbA[j] = *(const f32x4*)&zrow[j * 4];

        for (int t0 = 0; t0 < SEQ; t0 += 16) {
            scan_body8(t0,     zrow, hlrow, writer, zbA, zbB, hx, cx,
                       wp, cth, k0, k1, k2, k3, k4, one_i);
            scan_body8(t0 + 8, zrow, hlrow, writer, zbB, zbA, hx, cx,
                       wp, cth, k0, k1, k2, k3, k4, one_i);
        }

        if (hi == 0 && tx < 32) {
            out[NROWS * 8 + oidx]        = hx;   // final hx (512,8)
            out[NROWS * 8 + 4096 + oidx] = cx;   // final cx (512,8)
        }
    }
    __syncthreads();

    // ---- phase 3: gather-transpose dump of hx history (all 8 waves) --------
    {
        const int f0 = tx * 8;               // 0..4095
        const int t  = f0 >> 4;              // 0..255
        const int c0 = f0 & 15;              // 0 or 8
        float4 v0, v1;
        v0.x = Hl2[(c0 + 0) * HLSTR + t];
        v0.y = Hl2[(c0 + 1) * HLSTR + t];
        v0.z = Hl2[(c0 + 2) * HLSTR + t];
        v0.w = Hl2[(c0 + 3) * HLSTR + t];
        v1.x = Hl2[(c0 + 4) * HLSTR + t];
        v1.y = Hl2[(c0 + 5) * HLSTR + t];
        v1.z = Hl2[(c0 + 6) * HLSTR + t];
        v1.w = Hl2[(c0 + 7) * HLSTR + t];
        float4* dst = (float4*)(out + (long)t * (BATCH * 8) + B0 * 16 + c0);
        dst[0] = v0;
        dst[1] = v1;
    }
}

// ---------------------------------------------------------------------------
extern "C" void kernel_launch(void* const* d_in, const int* in_sizes, int n_in,
                              void* d_out, int out_size, void* d_ws, size_t ws_size,
                              hipStream_t stream) {
    const float* X   = (const float*)d_in[0];
    const float* Wf  = (const float*)d_in[1];
    const float* bfv = (const float*)d_in[2];
    const float* Wi  = (const float*)d_in[3];
    const float* biv = (const float*)d_in[4];
    const float* Wu  = (const float*)d_in[5];
    const float* buv = (const float*)d_in[6];
    const float* Wo  = (const float*)d_in[7];
    const float* bov = (const float*)d_in[8];
    const float* pf  = (const float*)d_in[9];
    const float* pi_ = (const float*)d_in[10];
    const float* pu  = (const float*)d_in[11];
    const float* po  = (const float*)d_in[12];
    float* out = (float*)d_out;
    (void)d_ws; (void)ws_size;               // workspace not needed

    qlstm_fused<<<BATCH / 2, 512, 0, stream>>>(
        X, Wf, Wi, Wu, Wo, bfv, biv, buv, bov, pf, pi_, pu, po, out);
}

// Round 5
// 249.807 us; speedup vs baseline: 1.0694x; 1.0003x over previous
//
#include <hip/hip_runtime.h>
#include <hip/hip_bf16.h>

// ---------------------------------------------------------------------------
// QLSTM fused: seq=256, batch=512, input=256, H=n_qubits=8.
// ONE kernel, 256 blocks x 512 threads. Block b owns batches {2b, 2b+1}:
//   phase 1: 8 waves MFMA-gemm 512 (t,batch)-rows. NEW: X loaded with fully
//            coalesced 1-KB dwordx4 instructions (2 rows x 32 lanes), packed
//            to bf16, re-staged through a wave-private LDS tile, fragments
//            read back as ds_read_b128. Z -> Zt in LDS transposed per-stream.
//   phase 2: wave 0 runs the 256-step scan (unchanged, verified).
//   phase 3: all 8 waves gather-transpose the history and bulk-dump float4s.
// bf16 conversion uses the same __float22bfloat162_rn rounding as before ->
// Z and all downstream math bit-identical to R1..R4 (absmax 0.0078125).
// ---------------------------------------------------------------------------

#define SEQ   256
#define BATCH 512
#define DIN   256
#define NROWS (SEQ * BATCH)      // 131072
#define DCOMB 264                // 256 + 8
#define ZTSTR 514                // floats per (bl,q) stream: 512 + 2 pad
#define HLSTR 260                // floats per c-row of history: 256 + 4 pad
#define SROWB 272                // stage row stride in BYTES (256 + 16 pad)

typedef __attribute__((ext_vector_type(8))) short short8;
typedef __attribute__((ext_vector_type(4))) float f32x4;
typedef __attribute__((ext_vector_type(2))) float f32x2;

__device__ __forceinline__ short f2bf(float f) {
    union { __hip_bfloat16 h; short s; } u;
    u.h = __float2bfloat16(f);
    return u.s;
}
__device__ __forceinline__ float bf2f(short s) {
    union { short s; __hip_bfloat16 h; } u;
    u.s = s;
    return __bfloat162float(u.h);
}

// DPP conventions (verified): row_shr:d -> dst[i]=src[i-d], invalid -> old;
// row_ror:s -> dst[i]=src[(i-s) mod 16]; quad_perm ctrl in [0,0xFF].
#define DPP_ROR(V, S) \
    __int_as_float(__builtin_amdgcn_update_dpp(__float_as_int(V), __float_as_int(V), 0x120 | (S), 0xF, 0xF, false))
#define QP(V, CTRL) \
    __int_as_float(__builtin_amdgcn_update_dpp(__float_as_int(V), __float_as_int(V), (CTRL), 0xF, 0xF, false))
// prefix-product stage, shift D lanes (= D/2 qubits); shifted-in value = 1.0
#define PSTG2(A, D) { \
    float s0_ = __int_as_float(__builtin_amdgcn_update_dpp(one_i, __float_as_int(A.x), 0x110 | (D), 0xF, 0xF, false)); \
    float s1_ = __int_as_float(__builtin_amdgcn_update_dpp(one_i, __float_as_int(A.y), 0x110 | (D), 0xF, 0xF, false)); \
    A *= (f32x2){s0_, s1_}; }

// one 8-step scan body: consume ZC (chunk T0), prefetch ZN (chunk T0+8),
// flush hx history for steps T0..T0+7. All indices static after inlining.
__device__ __forceinline__ void scan_body8(
    int T0, const float* __restrict__ zrow, float* __restrict__ hlrow,
    bool writer, f32x4 (&ZC)[4], f32x4 (&ZN)[4],
    float& hx, float& cx,
    const f32x2 (&wp)[8], const f32x2 cth,
    const f32x2 k0, const f32x2 k1, const f32x2 k2, const f32x2 k3,
    const f32x2 k4, const int one_i)
{
    // prefetch next chunk (body-length chain hides ds latency)
    #pragma unroll
    for (int j = 0; j < 4; ++j)
        ZN[j] = *(const f32x4*)&zrow[(T0 + 8) * 2 + j * 4];

    float hxh[8];
    #pragma unroll
    for (int u = 0; u < 8; ++u) {
        const f32x2 z2 = (f32x2){ ZC[u >> 1][(u & 1) * 2],
                                  ZC[u >> 1][(u & 1) * 2 + 1] };

        // hx rotations (hx pair-duplicated; qubit shift s = lane ror 2s)
        const float h0 = hx;
        const float h1 = DPP_ROR(hx, 2),  h2 = DPP_ROR(hx, 4);
        const float h3 = DPP_ROR(hx, 6),  h4 = DPP_ROR(hx, 8);
        const float h5 = DPP_ROR(hx, 10), h6 = DPP_ROR(hx, 12);
        const float h7 = DPP_ROR(hx, 14);

        // pre-pair = z + hx @ Wh.T (balanced fma tree)
        f32x2 e0 = (f32x2){h0, h0} * wp[0] + (f32x2){h1, h1} * wp[1];
        f32x2 e1 = (f32x2){h2, h2} * wp[2] + (f32x2){h3, h3} * wp[3];
        f32x2 e2 = (f32x2){h4, h4} * wp[4] + (f32x2){h5, h5} * wp[5];
        f32x2 e3 = (f32x2){h6, h6} * wp[6] + (f32x2){h7, h7} * wp[7];
        const f32x2 p = ((z2 + e0) + (e1 + e2)) + e3;

        // qgate: a = cos(pre)*cos(theta), then qubit prefix product
        f32x2 A = (f32x2){__cosf(p.x), __cosf(p.y)} * cth;
        PSTG2(A, 2) PSTG2(A, 4) PSTG2(A, 8)

        // activations via per-lane poly (|A|<=1)
        const f32x2 t2 = A * A;
        f32x2 rr = k3 + t2 * k4;
        rr = k2 + t2 * rr;
        rr = k1 + t2 * rr;
        const f32x2 P = k0 + A * rr;

        // broadcast all 4 gates to both lanes of the pair (quad_perm)
        const float f_all = QP(P.x, 0xA0);   // [0,0,2,2]
        const float u_all = QP(P.x, 0xF5);   // [1,1,3,3]
        const float i_all = QP(P.y, 0xA0);
        const float o_all = QP(P.y, 0xF5);

        // cx = f*cx + i*u   (valid in ALL lanes, pair-duplicated)
        cx = fmaf(f_all, cx, i_all * u_all);

        // tanh(cx) via Pade[5/4] (|cx| <= ~2.1), 1 rcp
        const float tq  = cx * cx;
        const float num = cx * fmaf(tq, fmaf(tq, 1.0f, 105.0f), 945.0f);
        const float den = fmaf(tq, fmaf(tq, 15.0f, 420.0f), 945.0f);
        const float tc  = num * __builtin_amdgcn_rcpf(den);

        // hx = o * tanh(cx) — valid in all lanes
        hx = o_all * tc;
        hxh[u] = hx;
    }

    if (writer) {
        *(f32x4*)&hlrow[T0]     = (f32x4){hxh[0], hxh[1], hxh[2], hxh[3]};
        *(f32x4*)&hlrow[T0 + 4] = (f32x4){hxh[4], hxh[5], hxh[6], hxh[7]};
    }
}

__global__ __launch_bounds__(512, 2) void qlstm_fused(
    const float* __restrict__ X,
    const float* __restrict__ Wf, const float* __restrict__ Wi,
    const float* __restrict__ Wu, const float* __restrict__ Wo,
    const float* __restrict__ bfv, const float* __restrict__ biv,
    const float* __restrict__ buv, const float* __restrict__ bov,
    const float* __restrict__ pf, const float* __restrict__ pi_,
    const float* __restrict__ pu, const float* __restrict__ po,
    float* __restrict__ out)
{
    // [nt(2)][hl(2)][ks(8)][lane(64)] bf16 B-fragments: 2048 * 16 B = 32 KB
    __shared__ short8 Wl[2048];
    // Zt transposed: stream per (bl,q): [bl*16+q][t*2+comp], stride 514,
    // +16 tail pad for the final body's harmless over-prefetch. 64.3 KB
    __shared__ float Zt[32 * ZTSTR + 16];
    // Stage: phase-1 X half-tiles, 128 rows x 272 B = 34 KB. Reused in
    // phase 2/3 as the hx history [c][t] (disjoint lifetimes).
    __shared__ float StageU[(128 * SROWB) / 4];

    const int tx  = threadIdx.x;
    const int l   = tx & 63;
    const int wid = tx >> 6;
    const int lm  = l & 15;
    const int lk  = l >> 4;
    const int B0  = blockIdx.x;              // batch pair index

    const float* Wg[4] = {Wf, Wi, Wu, Wo};
    const float* Bg[4] = {bfv, biv, buv, bov};

    // ---- preamble: convert W -> LDS bf16 hi/lo fragments (once per block) ---
    #pragma unroll
    for (int e = 0; e < 4; ++e) {
        const int ent  = tx + e * 512;       // 0..2047
        const int lane = ent & 63;
        const int ks   = (ent >> 6) & 7;
        const int hl   = (ent >> 9) & 1;
        const int nt   = (ent >> 10) & 1;
        const int elm  = lane & 15, elk = lane >> 4;
        const int c    = nt * 16 + elm;      // col = kq*4 + g
        const float* wrow = Wg[c & 3] + (c >> 2) * DCOMB + ks * 32 + elk * 8;
        short8 fr;
        #pragma unroll
        for (int j = 0; j < 8; ++j) {
            const float v = wrow[j];
            const short h16 = f2bf(v);
            fr[j] = hl ? f2bf(v - bf2f(h16)) : h16;
        }
        Wl[ent] = fr;
    }

    // bias per lane (bias of output col = lane's D column)
    float bias0, bias1;
    { const int c0 = lm;      bias0 = Bg[c0 & 3][c0 >> 2];
      const int c1 = 16 + lm; bias1 = Bg[c1 & 3][c1 >> 2]; }

    __syncthreads();

    // ---- phase 1: gemm, 4 passes x 8 waves x 16 rows (wave-private) --------
    // local row r = 2t + bl;  global X row = t*BATCH + (2*B0 + bl)
    char* const stage = (char*)StageU;
    #pragma unroll 1
    for (int p = 0; p < 4; ++p) {
        const int r0 = p * 128 + wid * 16;

        // 16 fully-coalesced 1-KB loads: j&7 = row-pair, j>>3 = col-half.
        // lanes 0-31 -> row r0+2(j&7) (bl=0), lanes 32-63 -> +1 (bl=1).
        float4 xv[16];
        #pragma unroll
        for (int j = 0; j < 16; ++j) {
            const int rl = r0 + 2 * (j & 7) + (l >> 5);
            const float* src =
                X + ((long)(rl >> 1) * BATCH + B0 * 2 + (rl & 1)) * DIN
                  + (j >> 3) * 128 + (l & 31) * 4;
            xv[j] = *(const float4*)src;
        }

        f32x4 acc0 = (f32x4){bias0, bias0, bias0, bias0};
        f32x4 acc1 = (f32x4){bias1, bias1, bias1, bias1};

        #pragma unroll
        for (int h = 0; h < 2; ++h) {
            // stage this col-half as bf16 into the wave-private LDS tile
            #pragma unroll
            for (int jj = 0; jj < 8; ++jj) {
                const int j = h * 8 + jj;
                const int row_s = wid * 16 + 2 * (j & 7) + (l >> 5);
                union { uint2 u2; __hip_bfloat162 h2[2]; } pk;
                pk.h2[0] = __float22bfloat162_rn(make_float2(xv[j].x, xv[j].y));
                pk.h2[1] = __float22bfloat162_rn(make_float2(xv[j].z, xv[j].w));
                *(uint2*)(stage + row_s * SROWB + (l & 31) * 8) = pk.u2;
            }
            // A-fragments (row lm, k-window ks*32+lk*8 within this half) + MFMA
            #pragma unroll
            for (int ks = 0; ks < 4; ++ks) {
                const short8 a = *(const short8*)
                    (stage + (wid * 16 + lm) * SROWB + (ks * 4 + lk) * 16);
                const int ka = h * 4 + ks;
                acc0 = __builtin_amdgcn_mfma_f32_16x16x32_bf16(a, Wl[ka * 64 + l],        acc0, 0, 0, 0);
                acc0 = __builtin_amdgcn_mfma_f32_16x16x32_bf16(a, Wl[(8  + ka) * 64 + l], acc0, 0, 0, 0);
                acc1 = __builtin_amdgcn_mfma_f32_16x16x32_bf16(a, Wl[(16 + ka) * 64 + l], acc1, 0, 0, 0);
                acc1 = __builtin_amdgcn_mfma_f32_16x16x32_bf16(a, Wl[(24 + ka) * 64 + l], acc1, 0, 0, 0);
            }
        }

        // D layout: col = lane&15, row = (lane>>4)*4 + reg. Scatter into the
        // transposed stream: (r, c) -> Zt[(r&1)*16 + (c>>1)][(r>>1)*2 + (c&1)]
        #pragma unroll
        for (int rr = 0; rr < 4; ++rr) {
            const int rw = r0 + lk * 4 + rr;
            const int tt = rw >> 1, blw = rw & 1;
            Zt[(blw * 16 + (lm >> 1)) * ZTSTR + tt * 2 + (lm & 1)]     = acc0[rr];
            Zt[(blw * 16 + 8 + (lm >> 1)) * ZTSTR + tt * 2 + (lm & 1)] = acc1[rr];
        }
    }
    __syncthreads();

    // ---- phase 2: scan (wave 0 only; waves 1..7 wait at the barrier) -------
    float* const Hl2 = StageU;               // stage region reused as history
    if (tx < 64) {
        const int q   = tx & 15;             // lane-in-batch 0..15
        const int kq  = q >> 1;              // qubit index
        const int hi  = q & 1;               // 0: gates (f,i); 1: (u,o)
        const int bl  = (tx >> 4) & 1;       // batch-in-pair (mirrored 32-63)
        const int b   = B0 * 2 + bl;
        const int oidx = b * 8 + kq;
        const int woff = kq * DCOMB + DIN;

        const float* WgA = hi ? Wu : Wf;
        const float* WgB = hi ? Wo : Wi;
        f32x2 wp[8];                         // rotated recurrent weights
        #pragma unroll
        for (int s = 0; s < 8; ++s) {
            const int j = (kq - s) & 7;
            wp[s] = (f32x2){WgA[woff + j], WgB[woff + j]};
        }
        const f32x2 cth = (f32x2){__cosf((hi ? pu : pf)[kq]),
                                  __cosf((hi ? po : pi_)[kq])};

        // activation poly: act(x) = k0 + x*(k1 + t*(k2 + t*(k3 + t*k4))), t=x^2
        const float SK1 = 0.25f, SK2 = -0.0208333333f, SK3 = 0.0020833333f,
                    SK4 = -0.00021082f;
        const f32x2 k0 = (f32x2){hi ? 0.0f : 0.5f, 0.5f};
        const f32x2 k1 = (f32x2){hi ? 0.9999016f : SK1, SK1};
        const f32x2 k2 = (f32x2){hi ? -0.3310485f : SK2, SK2};
        const f32x2 k3 = (f32x2){hi ? 0.1204423f : SK3, SK3};
        const f32x2 k4 = (f32x2){hi ? -0.0277012f : SK4, SK4};

        const int one_i = __float_as_int(1.0f);

        float hx = 0.0f, cx = 0.0f;
        const float* __restrict__ zrow = &Zt[(bl * 16 + q) * ZTSTR];
        float* __restrict__ hlrow = &Hl2[(bl * 8 + kq) * HLSTR];
        const bool writer = (hi == 0) && (tx < 32);

        f32x4 zbA[4], zbB[4];
        #pragma unroll
        for (int j = 0; j < 4; ++j) zbA[j] = *(const f32x4*)&zrow[j * 4];

        for (int t0 = 0; t0 < SEQ; t0 += 16) {
            scan_body8(t0,     zrow, hlrow, writer, zbA, zbB, hx, cx,
                       wp, cth, k0, k1, k2, k3, k4, one_i);
            scan_body8(t0 + 8, zrow, hlrow, writer, zbB, zbA, hx, cx,
                       wp, cth, k0, k1, k2, k3, k4, one_i);
        }

        if (hi == 0 && tx < 32) {
            out[NROWS * 8 + oidx]        = hx;   // final hx (512,8)
            out[NROWS * 8 + 4096 + oidx] = cx;   // final cx (512,8)
        }
    }
    __syncthreads();

    // ---- phase 3: gather-transpose dump of hx history (all 8 waves) --------
    {
        const int f0 = tx * 8;               // 0..4095
        const int t  = f0 >> 4;              // 0..255
        const int c0 = f0 & 15;              // 0 or 8
        float4 v0, v1;
        v0.x = Hl2[(c0 + 0) * HLSTR + t];
        v0.y = Hl2[(c0 + 1) * HLSTR + t];
        v0.z = Hl2[(c0 + 2) * HLSTR + t];
        v0.w = Hl2[(c0 + 3) * HLSTR + t];
        v1.x = Hl2[(c0 + 4) * HLSTR + t];
        v1.y = Hl2[(c0 + 5) * HLSTR + t];
        v1.z = Hl2[(c0 + 6) * HLSTR + t];
        v1.w = Hl2[(c0 + 7) * HLSTR + t];
        float4* dst = (float4*)(out + (long)t * (BATCH * 8) + B0 * 16 + c0);
        dst[0] = v0;
        dst[1] = v1;
    }
}

// ---------------------------------------------------------------------------
extern "C" void kernel_launch(void* const* d_in, const int* in_sizes, int n_in,
                              void* d_out, int out_size, void* d_ws, size_t ws_size,
                              hipStream_t stream) {
    const float* X   = (const float*)d_in[0];
    const float* Wf  = (const float*)d_in[1];
    const float* bfv = (const float*)d_in[2];
    const float* Wi  = (const float*)d_in[3];
    const float* biv = (const float*)d_in[4];
    const float* Wu  = (const float*)d_in[5];
    const float* buv = (const float*)d_in[6];
    const float* Wo  = (const float*)d_in[7];
    const float* bov = (const float*)d_in[8];
    const float* pf  = (const float*)d_in[9];
    const float* pi_ = (const float*)d_in[10];
    const float* pu  = (const float*)d_in[11];
    const float* po  = (const float*)d_in[12];
    float* out = (float*)d_out;
    (void)d_ws; (void)ws_size;               // workspace not needed

    qlstm_fused<<<BATCH / 2, 512, 0, stream>>>(
        X, Wf, Wi, Wu, Wo, bfv, biv, buv, bov, pf, pi_, pu, po, out);
}

// Round 6
// 220.313 us; speedup vs baseline: 1.2126x; 1.1339x over previous
//
#include <hip/hip_runtime.h>
#include <hip/hip_bf16.h>

// ---------------------------------------------------------------------------
// QLSTM fused pipelined: seq=256, batch=512, input=256, H=n_qubits=8.
// ONE kernel, 256 blocks x 512 threads. Block b owns batches {2b, 2b+1}.
// Producer-consumer pipeline over 4 chunks of 64 timesteps:
//   wave 0     : scans chunk k-1 from LDS ring buffer (256-step recurrence)
//   waves 1-4  : MFMA-gemm chunk k (128 local rows) into the other buffer
//   waves 5-7  : idle at barriers
//   one __syncthreads per chunk iteration (5 total).
// kernel ~= max(gemm, scan) instead of sum. Scan math bit-identical to
// R1..R5 (verified, absmax 0.0078125).
// ---------------------------------------------------------------------------

#define SEQ   256
#define BATCH 512
#define DIN   256
#define NROWS (SEQ * BATCH)      // 131072
#define DCOMB 264                // 256 + 8
#define CHT   64                 // timesteps per chunk
#define NCH   (SEQ / CHT)        // 4 chunks
#define ZBSTR 130                // floats per (bl,q) stream in a chunk buffer
#define ZBUFSZ (32 * ZBSTR + 16) // +16 pad: last body's harmless over-prefetch
#define HLSTR 260                // floats per c-row of history: 256 + 4 pad

typedef __attribute__((ext_vector_type(8))) short short8;
typedef __attribute__((ext_vector_type(4))) float f32x4;
typedef __attribute__((ext_vector_type(2))) float f32x2;

__device__ __forceinline__ short f2bf(float f) {
    union { __hip_bfloat16 h; short s; } u;
    u.h = __float2bfloat16(f);
    return u.s;
}
__device__ __forceinline__ float bf2f(short s) {
    union { short s; __hip_bfloat16 h; } u;
    u.s = s;
    return __bfloat162float(u.h);
}

__device__ __forceinline__ short8 pack8(float4 a, float4 b) {
    union { short8 s8; int i[4]; } u;
    union { __hip_bfloat162 h; int i; } v;
    v.h = __float22bfloat162_rn(make_float2(a.x, a.y)); u.i[0] = v.i;
    v.h = __float22bfloat162_rn(make_float2(a.z, a.w)); u.i[1] = v.i;
    v.h = __float22bfloat162_rn(make_float2(b.x, b.y)); u.i[2] = v.i;
    v.h = __float22bfloat162_rn(make_float2(b.z, b.w)); u.i[3] = v.i;
    return u.s8;
}

// DPP conventions (verified): row_shr:d -> dst[i]=src[i-d], invalid -> old;
// row_ror:s -> dst[i]=src[(i-s) mod 16]; quad_perm ctrl in [0,0xFF].
#define DPP_ROR(V, S) \
    __int_as_float(__builtin_amdgcn_update_dpp(__float_as_int(V), __float_as_int(V), 0x120 | (S), 0xF, 0xF, false))
#define QP(V, CTRL) \
    __int_as_float(__builtin_amdgcn_update_dpp(__float_as_int(V), __float_as_int(V), (CTRL), 0xF, 0xF, false))
// prefix-product stage, shift D lanes (= D/2 qubits); shifted-in value = 1.0
#define PSTG2(A, D) { \
    float s0_ = __int_as_float(__builtin_amdgcn_update_dpp(one_i, __float_as_int(A.x), 0x110 | (D), 0xF, 0xF, false)); \
    float s1_ = __int_as_float(__builtin_amdgcn_update_dpp(one_i, __float_as_int(A.y), 0x110 | (D), 0xF, 0xF, false)); \
    A *= (f32x2){s0_, s1_}; }

// one 8-step scan body: consume ZC (local chunk offset T0L), prefetch ZN
// (T0L+8; last body over-prefetches into pad, never consumed), flush hx
// history for global steps T0G..T0G+7. Indices static after inlining.
__device__ __forceinline__ void scan_body8(
    int T0L, int T0G, const float* __restrict__ zrow,
    float* __restrict__ hlrow, bool writer,
    f32x4 (&ZC)[4], f32x4 (&ZN)[4],
    float& hx, float& cx,
    const f32x2 (&wp)[8], const f32x2 cth,
    const f32x2 k0, const f32x2 k1, const f32x2 k2, const f32x2 k3,
    const f32x2 k4, const int one_i)
{
    #pragma unroll
    for (int j = 0; j < 4; ++j)
        ZN[j] = *(const f32x4*)&zrow[(T0L + 8) * 2 + j * 4];

    float hxh[8];
    #pragma unroll
    for (int u = 0; u < 8; ++u) {
        const f32x2 z2 = (f32x2){ ZC[u >> 1][(u & 1) * 2],
                                  ZC[u >> 1][(u & 1) * 2 + 1] };

        // hx rotations (hx pair-duplicated; qubit shift s = lane ror 2s)
        const float h0 = hx;
        const float h1 = DPP_ROR(hx, 2),  h2 = DPP_ROR(hx, 4);
        const float h3 = DPP_ROR(hx, 6),  h4 = DPP_ROR(hx, 8);
        const float h5 = DPP_ROR(hx, 10), h6 = DPP_ROR(hx, 12);
        const float h7 = DPP_ROR(hx, 14);

        // pre-pair = z + hx @ Wh.T (balanced fma tree)
        f32x2 e0 = (f32x2){h0, h0} * wp[0] + (f32x2){h1, h1} * wp[1];
        f32x2 e1 = (f32x2){h2, h2} * wp[2] + (f32x2){h3, h3} * wp[3];
        f32x2 e2 = (f32x2){h4, h4} * wp[4] + (f32x2){h5, h5} * wp[5];
        f32x2 e3 = (f32x2){h6, h6} * wp[6] + (f32x2){h7, h7} * wp[7];
        const f32x2 p = ((z2 + e0) + (e1 + e2)) + e3;

        // qgate: a = cos(pre)*cos(theta), then qubit prefix product
        f32x2 A = (f32x2){__cosf(p.x), __cosf(p.y)} * cth;
        PSTG2(A, 2) PSTG2(A, 4) PSTG2(A, 8)

        // activations via per-lane poly (|A|<=1)
        const f32x2 t2 = A * A;
        f32x2 rr = k3 + t2 * k4;
        rr = k2 + t2 * rr;
        rr = k1 + t2 * rr;
        const f32x2 P = k0 + A * rr;

        // broadcast all 4 gates to both lanes of the pair (quad_perm)
        const float f_all = QP(P.x, 0xA0);   // [0,0,2,2]
        const float u_all = QP(P.x, 0xF5);   // [1,1,3,3]
        const float i_all = QP(P.y, 0xA0);
        const float o_all = QP(P.y, 0xF5);

        // cx = f*cx + i*u   (valid in ALL lanes, pair-duplicated)
        cx = fmaf(f_all, cx, i_all * u_all);

        // tanh(cx) via Pade[5/4] (|cx| <= ~2.1), 1 rcp
        const float tq  = cx * cx;
        const float num = cx * fmaf(tq, fmaf(tq, 1.0f, 105.0f), 945.0f);
        const float den = fmaf(tq, fmaf(tq, 15.0f, 420.0f), 945.0f);
        const float tc  = num * __builtin_amdgcn_rcpf(den);

        // hx = o * tanh(cx) — valid in all lanes
        hx = o_all * tc;
        hxh[u] = hx;
    }

    if (writer) {
        *(f32x4*)&hlrow[T0G]     = (f32x4){hxh[0], hxh[1], hxh[2], hxh[3]};
        *(f32x4*)&hlrow[T0G + 4] = (f32x4){hxh[4], hxh[5], hxh[6], hxh[7]};
    }
}

__global__ __launch_bounds__(512, 1) void qlstm_fused(
    const float* __restrict__ X,
    const float* __restrict__ Wf, const float* __restrict__ Wi,
    const float* __restrict__ Wu, const float* __restrict__ Wo,
    const float* __restrict__ bfv, const float* __restrict__ biv,
    const float* __restrict__ buv, const float* __restrict__ bov,
    const float* __restrict__ pf, const float* __restrict__ pi_,
    const float* __restrict__ pu, const float* __restrict__ po,
    float* __restrict__ out)
{
    // [nt(2)][hl(2)][ks(8)][lane(64)] bf16 B-fragments: 2048 * 16 B = 32 KB
    __shared__ short8 Wl[2048];
    // double-buffered Z chunk ring: [2][stream 0..31][t_local*2+comp]. 32.6 KB
    __shared__ float Zb[2][ZBUFSZ];
    // hx history: [c = bl*8+kq][t], stride 260. 16.25 KB
    __shared__ float Hl2[16 * HLSTR];

    const int tx  = threadIdx.x;
    const int l   = tx & 63;
    const int wid = tx >> 6;
    const int lm  = l & 15;
    const int lk  = l >> 4;
    const int B0  = blockIdx.x;              // batch pair index

    const float* Wg[4] = {Wf, Wi, Wu, Wo};
    const float* Bg[4] = {bfv, biv, buv, bov};

    // ---- preamble: convert W -> LDS bf16 hi/lo fragments (once per block) ---
    #pragma unroll
    for (int e = 0; e < 4; ++e) {
        const int ent  = tx + e * 512;       // 0..2047
        const int lane = ent & 63;
        const int ks   = (ent >> 6) & 7;
        const int hl   = (ent >> 9) & 1;
        const int nt   = (ent >> 10) & 1;
        const int elm  = lane & 15, elk = lane >> 4;
        const int c    = nt * 16 + elm;      // col = kq*4 + g
        const float* wrow = Wg[c & 3] + (c >> 2) * DCOMB + ks * 32 + elk * 8;
        short8 fr;
        #pragma unroll
        for (int j = 0; j < 8; ++j) {
            const float v = wrow[j];
            const short h16 = f2bf(v);
            fr[j] = hl ? f2bf(v - bf2f(h16)) : h16;
        }
        Wl[ent] = fr;
    }

    // bias per lane (bias of output col = lane's D column) — producers use
    float bias0, bias1;
    { const int c0 = lm;      bias0 = Bg[c0 & 3][c0 >> 2];
      const int c1 = 16 + lm; bias1 = Bg[c1 & 3][c1 >> 2]; }

    // ---- scanner state (wave 0 lanes only; cheap to set up) ----------------
    const int q   = tx & 15;                 // lane-in-batch 0..15
    const int kq  = q >> 1;                  // qubit index
    const int hi  = q & 1;                   // 0: gates (f,i); 1: (u,o)
    const int bl  = (tx >> 4) & 1;           // batch-in-pair (mirrored 32-63)
    const int oidx = (B0 * 2 + bl) * 8 + kq;
    const int woff = kq * DCOMB + DIN;

    f32x2 wp[8];
    f32x2 cth = (f32x2){1.0f, 1.0f};
    if (wid == 0) {
        const float* WgA = hi ? Wu : Wf;
        const float* WgB = hi ? Wo : Wi;
        #pragma unroll
        for (int s = 0; s < 8; ++s) {
            const int j = (kq - s) & 7;
            wp[s] = (f32x2){WgA[woff + j], WgB[woff + j]};
        }
        cth = (f32x2){__cosf((hi ? pu : pf)[kq]),
                      __cosf((hi ? po : pi_)[kq])};
    }
    // activation poly: act(x) = k0 + x*(k1 + t*(k2 + t*(k3 + t*k4))), t=x^2
    const float SK1 = 0.25f, SK2 = -0.0208333333f, SK3 = 0.0020833333f,
                SK4 = -0.00021082f;
    const f32x2 k0 = (f32x2){hi ? 0.0f : 0.5f, 0.5f};
    const f32x2 k1 = (f32x2){hi ? 0.9999016f : SK1, SK1};
    const f32x2 k2 = (f32x2){hi ? -0.3310485f : SK2, SK2};
    const f32x2 k3 = (f32x2){hi ? 0.1204423f : SK3, SK3};
    const f32x2 k4 = (f32x2){hi ? -0.0277012f : SK4, SK4};
    const int one_i = __float_as_int(1.0f);

    float hx = 0.0f, cx = 0.0f;
    const float* __restrict__ zrowb = &Zb[0][(bl * 16 + q) * ZBSTR];
    float* __restrict__ hlrow = &Hl2[(bl * 8 + kq) * HLSTR];
    const bool writer = (hi == 0) && (tx < 32);
    f32x4 zbA[4], zbB[4];

    __syncthreads();

    // ---- pipeline: 5 iterations; produce chunk k || scan chunk k-1 ---------
    #pragma unroll 1
    for (int k = 0; k <= NCH; ++k) {
        if (wid == 0) {
            if (k >= 1) {
                // scan chunk k-1 (64 steps) from Zb[(k-1)&1]
                const float* __restrict__ zrow = zrowb + ((k - 1) & 1) * ZBUFSZ;
                const int TG = (k - 1) * CHT;
                #pragma unroll
                for (int j = 0; j < 4; ++j) zbA[j] = *(const f32x4*)&zrow[j * 4];
                scan_body8( 0, TG,      zrow, hlrow, writer, zbA, zbB, hx, cx, wp, cth, k0, k1, k2, k3, k4, one_i);
                scan_body8( 8, TG + 8,  zrow, hlrow, writer, zbB, zbA, hx, cx, wp, cth, k0, k1, k2, k3, k4, one_i);
                scan_body8(16, TG + 16, zrow, hlrow, writer, zbA, zbB, hx, cx, wp, cth, k0, k1, k2, k3, k4, one_i);
                scan_body8(24, TG + 24, zrow, hlrow, writer, zbB, zbA, hx, cx, wp, cth, k0, k1, k2, k3, k4, one_i);
                scan_body8(32, TG + 32, zrow, hlrow, writer, zbA, zbB, hx, cx, wp, cth, k0, k1, k2, k3, k4, one_i);
                scan_body8(40, TG + 40, zrow, hlrow, writer, zbB, zbA, hx, cx, wp, cth, k0, k1, k2, k3, k4, one_i);
                scan_body8(48, TG + 48, zrow, hlrow, writer, zbA, zbB, hx, cx, wp, cth, k0, k1, k2, k3, k4, one_i);
                scan_body8(56, TG + 56, zrow, hlrow, writer, zbB, zbA, hx, cx, wp, cth, k0, k1, k2, k3, k4, one_i);
                if (k == NCH && writer) {
                    out[NROWS * 8 + oidx]        = hx;   // final hx (512,8)
                    out[NROWS * 8 + 4096 + oidx] = cx;   // final cx (512,8)
                }
            }
        } else if (wid <= 4 && k < NCH) {
            // produce chunk k (128 local rows) into Zb[k&1]
            float* __restrict__ bufp = &Zb[k & 1][0];
            #pragma unroll
            for (int g = 0; g < 2; ++g) {
                const int r0 = k * 128 + (wid - 1) * 32 + g * 16;
                const int r  = r0 + lm;      // this lane's A-row (= 2t+bl local)
                const float* xbase =
                    X + ((long)(r >> 1) * BATCH + B0 * 2 + (r & 1)) * DIN + lk * 8;

                float4 xv[16];
                #pragma unroll
                for (int i = 0; i < 16; ++i)
                    xv[i] = *(const float4*)(xbase + (i >> 1) * 32 + (i & 1) * 4);

                f32x4 acc0 = (f32x4){bias0, bias0, bias0, bias0};
                f32x4 acc1 = (f32x4){bias1, bias1, bias1, bias1};
                #pragma unroll
                for (int ks = 0; ks < 8; ++ks) {
                    const short8 a = pack8(xv[2 * ks], xv[2 * ks + 1]);
                    acc0 = __builtin_amdgcn_mfma_f32_16x16x32_bf16(a, Wl[ks * 64 + l],        acc0, 0, 0, 0);
                    acc0 = __builtin_amdgcn_mfma_f32_16x16x32_bf16(a, Wl[(8  + ks) * 64 + l], acc0, 0, 0, 0);
                    acc1 = __builtin_amdgcn_mfma_f32_16x16x32_bf16(a, Wl[(16 + ks) * 64 + l], acc1, 0, 0, 0);
                    acc1 = __builtin_amdgcn_mfma_f32_16x16x32_bf16(a, Wl[(24 + ks) * 64 + l], acc1, 0, 0, 0);
                }

                // D layout: col = lane&15, row = (lane>>4)*4 + reg.
                // (local r, col c) -> stream (r&1)*16 + (c>>1), idx tl*2+(c&1)
                #pragma unroll
                for (int rr = 0; rr < 4; ++rr) {
                    const int rw   = r0 + lk * 4 + rr;
                    const int tl   = (rw - k * 128) >> 1;
                    const int blw  = rw & 1;
                    bufp[(blw * 16 + (lm >> 1)) * ZBSTR + tl * 2 + (lm & 1)]     = acc0[rr];
                    bufp[(blw * 16 + 8 + (lm >> 1)) * ZBSTR + tl * 2 + (lm & 1)] = acc1[rr];
                }
            }
        }
        __syncthreads();
    }

    // ---- epilogue: gather-transpose dump of hx history (all 8 waves) -------
    {
        const int f0 = tx * 8;               // 0..4095
        const int t  = f0 >> 4;              // 0..255
        const int c0 = f0 & 15;              // 0 or 8
        float4 v0, v1;
        v0.x = Hl2[(c0 + 0) * HLSTR + t];
        v0.y = Hl2[(c0 + 1) * HLSTR + t];
        v0.z = Hl2[(c0 + 2) * HLSTR + t];
        v0.w = Hl2[(c0 + 3) * HLSTR + t];
        v1.x = Hl2[(c0 + 4) * HLSTR + t];
        v1.y = Hl2[(c0 + 5) * HLSTR + t];
        v1.z = Hl2[(c0 + 6) * HLSTR + t];
        v1.w = Hl2[(c0 + 7) * HLSTR + t];
        float4* dst = (float4*)(out + (long)t * (BATCH * 8) + B0 * 16 + c0);
        dst[0] = v0;
        dst[1] = v1;
    }
}

// ---------------------------------------------------------------------------
extern "C" void kernel_launch(void* const* d_in, const int* in_sizes, int n_in,
                              void* d_out, int out_size, void* d_ws, size_t ws_size,
                              hipStream_t stream) {
    const float* X   = (const float*)d_in[0];
    const float* Wf  = (const float*)d_in[1];
    const float* bfv = (const float*)d_in[2];
    const float* Wi  = (const float*)d_in[3];
    const float* biv = (const float*)d_in[4];
    const float* Wu  = (const float*)d_in[5];
    const float* buv = (const float*)d_in[6];
    const float* Wo  = (const float*)d_in[7];
    const float* bov = (const float*)d_in[8];
    const float* pf  = (const float*)d_in[9];
    const float* pi_ = (const float*)d_in[10];
    const float* pu  = (const float*)d_in[11];
    const float* po  = (const float*)d_in[12];
    float* out = (float*)d_out;
    (void)d_ws; (void)ws_size;               // workspace not needed

    qlstm_fused<<<BATCH / 2, 512, 0, stream>>>(
        X, Wf, Wi, Wu, Wo, bfv, biv, buv, bov, pf, pi_, pu, po, out);
}